// Round 11
// baseline (426.062 us; speedup 1.0000x reference)
//
#include <hip/hip_runtime.h>
#include <math.h>

#define T_TOK 65536
#define K_CODE 1024
#define E_DIM 64
#define DECAYF 0.99f
#define EPSF 1e-5f
#define MARG2 1.5e-4f  // bound on |dist_mfma - dist_emul| gap test; ~15x headroom

typedef __attribute__((ext_vector_type(8))) short short8;
typedef __attribute__((ext_vector_type(4))) float fx4;

// --- exact-rounding helpers: block ffp-contract=fast fusion ---
__device__ __forceinline__ float mul_nf(float a, float b) {
#pragma clang fp contract(off)
    return a * b;
}
__device__ __forceinline__ float add_nf(float a, float b) {
#pragma clang fp contract(off)
    return a + b;
}
__device__ __forceinline__ float sub_nf(float a, float b) {
#pragma clang fp contract(off)
    return a - b;
}

__device__ __forceinline__ unsigned short bf16_rn(float f) {
    union { float f; unsigned u; } v; v.f = f;
    unsigned r = v.u + 0x7fffu + ((v.u >> 16) & 1u);
    return (unsigned short)(r >> 16);
}
__device__ __forceinline__ float bf16_up(unsigned short h) {
    union { unsigned u; float f; } v; v.u = ((unsigned)h) << 16;
    return v.f;
}

// numpy pairwise_sum for n=64 of elementwise squares (products rounded
// separately, 8 strided accumulators, fixed combine tree).
__device__ __forceinline__ float np_sq_sum64(const float* v) {
    float r[8];
#pragma unroll
    for (int j = 0; j < 8; ++j) r[j] = mul_nf(v[j], v[j]);
#pragma unroll
    for (int i = 8; i < 64; i += 8) {
#pragma unroll
        for (int j = 0; j < 8; ++j) r[j] = add_nf(r[j], mul_nf(v[i + j], v[i + j]));
    }
    float s01 = add_nf(r[0], r[1]);
    float s23 = add_nf(r[2], r[3]);
    float s45 = add_nf(r[4], r[5]);
    float s67 = add_nf(r[6], r[7]);
    return add_nf(add_nf(s01, s23), add_nf(s45, s67));
}

// rows [0,T): np-exact ||x||^2 per token. rows [T, T+K): np-exact wnorm +
// bf16 hi/lo split of the code row.
__global__ __launch_bounds__(256) void prep_kernel(const float* __restrict__ z_e,
                                                   const float* __restrict__ embed,
                                                   float* __restrict__ xn_out,
                                                   float* __restrict__ wnorm_out,
                                                   unsigned short* __restrict__ whi,
                                                   unsigned short* __restrict__ wlo) {
    int row = blockIdx.x * 256 + threadIdx.x;
    if (row < T_TOK) {
        xn_out[row] = np_sq_sum64(z_e + (size_t)row * E_DIM);
    } else {
        int k = row - T_TOK;
        const float* w = embed + (size_t)k * E_DIM;
        wnorm_out[k] = np_sq_sum64(w);
#pragma unroll
        for (int i = 0; i < 64; ++i) {
            float e = w[i];
            unsigned short h = bf16_rn(e);
            whi[(size_t)k * 64 + i] = h;
            wlo[(size_t)k * 64 + i] = bf16_rn(e - bf16_up(h));
        }
    }
}

// Block = 256 thr = 4 waves; wave owns one 16-token M-tile, scans all 1024
// codes as 64 16-code N-tiles, unrolled x2 (8 B-frag loads hoisted per body).
// 3-pass bf16-split MFMA in 3 INDEPENDENT 2-deep chains (hh, lh, hl), summed
// in fp32. dist via the SAME np-exact xn/wn and same final rounding ops as
// the emulated path -> |dist_mfma - dist_emul| << MARG2.
// Per token-row: branch-free top-2 (m1,i1,m2). Exact dist_mfma ties give
// m2==m1 -> flagged. After cross-lane merge:
//   m2-m1 > MARG2 -> i1 is provably the np argmin
//   else          -> flag token for full exact rescan (epilogue)
// C/D layout (m89-verified): col=lane&15, row=(lane>>4)*4+reg.
// A/B layout: [mn=lane&15][k=(lane>>4)*8+j].
__global__ __launch_bounds__(256) void mfma_argmin_kernel(const float* __restrict__ z_e,
                                                          const float* __restrict__ xn_ws,
                                                          const float* __restrict__ wnorm_ws,
                                                          const unsigned short* __restrict__ whi,
                                                          const unsigned short* __restrict__ wlo,
                                                          float* __restrict__ out_ind,
                                                          float* __restrict__ flags) {
    int lane = threadIdx.x & 63;
    int wave = threadIdx.x >> 6;
    int quad = lane >> 4;
    int lmod = lane & 15;
    int t0 = blockIdx.x * 64 + wave * 16;

    // A fragments: token = t0+lmod, dims q*32 + quad*8 + j; bf16 hi/lo in-reg
    short8 ah[2], al[2];
#pragma unroll
    for (int q = 0; q < 2; ++q) {
        const float* xp = z_e + (size_t)(t0 + lmod) * E_DIM + q * 32 + quad * 8;
#pragma unroll
        for (int j = 0; j < 8; ++j) {
            float e = xp[j];
            unsigned short h = bf16_rn(e);
            ah[q][j] = (short)h;
            al[q][j] = (short)bf16_rn(e - bf16_up(h));
        }
    }

    // np-exact ||x||^2 for this lane's 4 C-row tokens (broadcast within quad)
    fx4 xnv = *(const fx4*)(xn_ws + t0 + quad * 4);

    float m1[4], m2[4];
    int i1[4];
#pragma unroll
    for (int r = 0; r < 4; ++r) { m1[r] = m2[r] = INFINITY; i1[r] = 0; }

    const unsigned short* hp = whi + (size_t)lmod * 64 + quad * 8;
    const unsigned short* lp = wlo + (size_t)lmod * 64 + quad * 8;

    for (int n = 0; n < 64; n += 2) {
        size_t o0 = (size_t)n * 1024;      // 16 rows x 64 shorts per tile
        size_t o1 = o0 + 1024;
        // all loads for both sub-tiles issue together (latency amortized)
        short8 bh00 = *(const short8*)(hp + o0);
        short8 bh01 = *(const short8*)(hp + o0 + 32);
        short8 bl00 = *(const short8*)(lp + o0);
        short8 bl01 = *(const short8*)(lp + o0 + 32);
        short8 bh10 = *(const short8*)(hp + o1);
        short8 bh11 = *(const short8*)(hp + o1 + 32);
        short8 bl10 = *(const short8*)(lp + o1);
        short8 bl11 = *(const short8*)(lp + o1 + 32);
        float wn0 = wnorm_ws[n * 16 + lmod];
        float wn1 = wnorm_ws[n * 16 + 16 + lmod];

        fx4 z = {0.f, 0.f, 0.f, 0.f};
        // sub-tile n: 3 independent 2-deep chains
        fx4 hh = __builtin_amdgcn_mfma_f32_16x16x32_bf16(ah[0], bh00, z, 0, 0, 0);
        hh = __builtin_amdgcn_mfma_f32_16x16x32_bf16(ah[1], bh01, hh, 0, 0, 0);
        fx4 lh = __builtin_amdgcn_mfma_f32_16x16x32_bf16(al[0], bh00, z, 0, 0, 0);
        lh = __builtin_amdgcn_mfma_f32_16x16x32_bf16(al[1], bh01, lh, 0, 0, 0);
        fx4 hl = __builtin_amdgcn_mfma_f32_16x16x32_bf16(ah[0], bl00, z, 0, 0, 0);
        hl = __builtin_amdgcn_mfma_f32_16x16x32_bf16(ah[1], bl01, hl, 0, 0, 0);
        // sub-tile n+1
        fx4 hh1 = __builtin_amdgcn_mfma_f32_16x16x32_bf16(ah[0], bh10, z, 0, 0, 0);
        hh1 = __builtin_amdgcn_mfma_f32_16x16x32_bf16(ah[1], bh11, hh1, 0, 0, 0);
        fx4 lh1 = __builtin_amdgcn_mfma_f32_16x16x32_bf16(al[0], bh10, z, 0, 0, 0);
        lh1 = __builtin_amdgcn_mfma_f32_16x16x32_bf16(al[1], bh11, lh1, 0, 0, 0);
        fx4 hl1 = __builtin_amdgcn_mfma_f32_16x16x32_bf16(ah[0], bl10, z, 0, 0, 0);
        hl1 = __builtin_amdgcn_mfma_f32_16x16x32_bf16(ah[1], bl11, hl1, 0, 0, 0);

        int code0 = n * 16 + lmod;
#pragma unroll
        for (int r = 0; r < 4; ++r) {
            float d = (hh[r] + lh[r]) + hl[r];
            float dist = add_nf(sub_nf(xnv[r], d + d), wn0);
            float t = fmaxf(m1[r], dist);
            m2[r] = fminf(m2[r], t);
            bool l = dist < m1[r];
            i1[r] = l ? code0 : i1[r];
            m1[r] = fminf(m1[r], dist);

            float d1 = (hh1[r] + lh1[r]) + hl1[r];
            float dist1 = add_nf(sub_nf(xnv[r], d1 + d1), wn1);
            float t1 = fmaxf(m1[r], dist1);
            m2[r] = fminf(m2[r], t1);
            bool l1 = dist1 < m1[r];
            i1[r] = l1 ? (code0 + 16) : i1[r];
            m1[r] = fminf(m1[r], dist1);
        }
    }

    // merge (m1,i1,m2) across the 16 lanes of each quad-group
#pragma unroll
    for (int s = 1; s < 16; s <<= 1) {
#pragma unroll
        for (int r = 0; r < 4; ++r) {
            float o1v = __shfl_xor(m1[r], s, 64);
            int oi = __shfl_xor(i1[r], s, 64);
            float o2v = __shfl_xor(m2[r], s, 64);
            float mx = fmaxf(m1[r], o1v);                 // loser of firsts
            m2[r] = fminf(fminf(m2[r], o2v), mx);         // second-min of union
            if (o1v < m1[r]) { m1[r] = o1v; i1[r] = oi; } // tie keeps self -> flagged anyway
        }
    }

    if (lmod == 0) {
#pragma unroll
        for (int r = 0; r < 4; ++r) {
            int token = t0 + quad * 4 + r;
            out_ind[token] = (float)i1[r];
            if (m2[r] - m1[r] <= MARG2) flags[token] = 1.0f;  // ambiguous -> exact rescan
        }
    }
}

// Per block: 64 tokens, 4 waves x 16 tokens. Flagged tokens get a full exact
// rescan (lane c handles codes c+64j, verified chain, np-first-index merge).
// Then z_q / straight-through / diff and the coalesced row-atomic EMA scatter.
__global__ __launch_bounds__(256) void epilogue_kernel(const float* __restrict__ z_e,
                                                       const float* __restrict__ embed,
                                                       const float* __restrict__ xn_ws,
                                                       const float* __restrict__ wnorm_ws,
                                                       float* __restrict__ out_ind,
                                                       const float* __restrict__ flags,
                                                       float* __restrict__ out_zq,
                                                       float* __restrict__ diff_acc,
                                                       float* __restrict__ esum_rep,
                                                       float* __restrict__ onehot_rep,
                                                       int rep_mask) {
    __shared__ float xs[4][64];
    int lane = threadIdx.x & 63;
    int wave = threadIdx.x >> 6;
    int rep = blockIdx.x & rep_mask;
    float* esum = esum_rep + (size_t)rep * (K_CODE * E_DIM);
    float* onehot = onehot_rep + (size_t)rep * K_CODE;
    int tbase = blockIdx.x * 64 + wave * 16;
    float ds = 0.f;

    for (int j = 0; j < 16; ++j) {
        int t = tbase + j;
        float xv = z_e[(size_t)t * E_DIM + lane];
        int bi = (int)out_ind[t];

        if (flags[t] != 0.f) {
            xs[wave][lane] = xv;
            __builtin_amdgcn_s_waitcnt(0xC07F);  // lgkmcnt(0): stage visible wave-wide
            float xn_t = xn_ws[t];
            float bestd = INFINITY;
            int besti = 0;
            for (int c = 0; c < 16; ++c) {
                int code = lane + (c << 6);
                const float* wr = embed + (size_t)code * E_DIM;
                float d = 0.f;
#pragma unroll
                for (int i = 0; i < 64; i += 4) {
                    float4 wc = *(const float4*)(wr + i);
                    d = __builtin_fmaf(xs[wave][i + 0], wc.x, d);
                    d = __builtin_fmaf(xs[wave][i + 1], wc.y, d);
                    d = __builtin_fmaf(xs[wave][i + 2], wc.z, d);
                    d = __builtin_fmaf(xs[wave][i + 3], wc.w, d);
                }
                float dist = add_nf(sub_nf(xn_t, d + d), wnorm_ws[code]);
                if (dist < bestd) { bestd = dist; besti = code; }  // ascending in-lane
            }
#pragma unroll
            for (int s = 1; s < 64; s <<= 1) {
                float od = __shfl_xor(bestd, s, 64);
                int oi = __shfl_xor(besti, s, 64);
                if (od < bestd || (od == bestd && oi < besti)) { bestd = od; besti = oi; }
            }
            bi = besti;
            if (lane == 0) out_ind[t] = (float)bi;
        }

        // np order: r = fl(z_q - z_e); out = fl(z_e + r)
        float wv = embed[(size_t)bi * E_DIM + lane];
        float rr = sub_nf(wv, xv);
        out_zq[(size_t)t * E_DIM + lane] = add_nf(xv, rr);
        ds = __builtin_fmaf(rr, rr, ds);

        atomicAdd(&esum[(size_t)bi * E_DIM + lane], xv);  // coalesced 256B row
        if (lane == 0) atomicAdd(&onehot[bi], 1.0f);
    }

#pragma unroll
    for (int o = 32; o > 0; o >>= 1) ds += __shfl_down(ds, o, 64);
    if (lane == 0) atomicAdd(diff_acc, ds);
}

// ncs, n, diff: single block (tiny)
__global__ __launch_bounds__(1024) void finalize_cs_kernel(const float* __restrict__ cluster_size,
                                                           const float* __restrict__ onehot_rep,
                                                           const float* __restrict__ ws_diff,
                                                           float* __restrict__ out_diff,
                                                           float* __restrict__ out_ncs,
                                                           float* __restrict__ ws_n,
                                                           int nrep) {
    int k = threadIdx.x;
    float oh = 0.f;
    for (int r = 0; r < nrep; ++r) oh += onehot_rep[(size_t)r * K_CODE + k];
    float ncs = DECAYF * cluster_size[k] + (1.0f - DECAYF) * oh;
    out_ncs[k] = ncs;

    __shared__ float red[1024];
    red[k] = ncs;
    __syncthreads();
#pragma unroll
    for (int s = 512; s > 0; s >>= 1) {
        if (k < s) red[k] += red[k + s];
        __syncthreads();
    }
    if (k == 0) {
        ws_n[0] = red[0];
        out_diff[0] = ws_diff[0] * (1.0f / 4194304.0f);  // /2^22 exact
    }
}

// embed_avg / embed update spread across 64 blocks
__global__ __launch_bounds__(256) void finalize_embed_kernel(const float* __restrict__ embed_avg,
                                                             const float* __restrict__ esum_rep,
                                                             const float* __restrict__ out_ncs,
                                                             const float* __restrict__ ws_n,
                                                             float* __restrict__ out_ne,
                                                             float* __restrict__ out_nea,
                                                             int nrep) {
    int gid = blockIdx.x * 256 + threadIdx.x;
    int k = gid >> 4;
    int c = gid & 15;
    float n = ws_n[0];
    float ncs = out_ncs[k];
    float cs = (ncs + EPSF) / (n + (float)K_CODE * EPSF) * n;

    size_t off = (size_t)k * E_DIM + (size_t)c * 4;
    float4 s4 = make_float4(0.f, 0.f, 0.f, 0.f);
    for (int r = 0; r < nrep; ++r) {
        float4 v = *reinterpret_cast<const float4*>(esum_rep + (size_t)r * (K_CODE * E_DIM) + off);
        s4.x += v.x; s4.y += v.y; s4.z += v.z; s4.w += v.w;
    }
    float4 a = *reinterpret_cast<const float4*>(embed_avg + off);
    float4 nea, ne;
    nea.x = DECAYF * a.x + (1.0f - DECAYF) * s4.x;
    nea.y = DECAYF * a.y + (1.0f - DECAYF) * s4.y;
    nea.z = DECAYF * a.z + (1.0f - DECAYF) * s4.z;
    nea.w = DECAYF * a.w + (1.0f - DECAYF) * s4.w;
    ne.x = nea.x / cs; ne.y = nea.y / cs; ne.z = nea.z / cs; ne.w = nea.w / cs;
    *reinterpret_cast<float4*>(out_nea + off) = nea;
    *reinterpret_cast<float4*>(out_ne + off) = ne;
}

extern "C" void kernel_launch(void* const* d_in, const int* in_sizes, int n_in,
                              void* d_out, int out_size, void* d_ws, size_t ws_size,
                              hipStream_t stream) {
    const float* z_e = (const float*)d_in[0];
    const float* embed = (const float*)d_in[1];
    const float* cluster_size = (const float*)d_in[2];
    const float* embed_avg = (const float*)d_in[3];

    float* out = (float*)d_out;
    float* o_zq = out;                   // 4194304
    float* o_diff = out + 4194304;       // 1
    float* o_ind = out + 4194305;        // 65536
    float* o_ne = out + 4194305 + 65536; // 65536
    float* o_ncs = o_ne + 65536;         // 1024
    float* o_nea = o_ncs + 1024;         // 65536

    // ws layout (floats), adaptive in nrep:
    // [0,1024) wnorm | [1024] diff | [1025] n | [2048,10240) onehot reps
    // [10240, E) esum reps, E = 10240 + nrep*65536
    // [E, +65536) xn | [+65536, +131072) flags
    // [+131072, +163840) w_hi (ushort) | [+163840, +196608) w_lo (ushort)
    int nrep = 8;
    while (nrep > 1 &&
           ws_size < (size_t)(10240 + (size_t)nrep * 65536 + 196608) * 4) nrep >>= 1;

    float* ws = (float*)d_ws;
    float* ws_wnorm = ws;
    float* ws_diff = ws + 1024;
    float* ws_n = ws + 1025;
    float* ws_onehot = ws + 2048;
    float* ws_esum = ws + 10240;
    size_t esum_end = 10240 + (size_t)nrep * 65536;
    float* ws_xn = ws + esum_end;
    float* ws_flags = ws + esum_end + 65536;
    unsigned short* ws_whi = (unsigned short*)(ws + esum_end + 131072);
    unsigned short* ws_wlo = (unsigned short*)(ws + esum_end + 163840);

    hipMemsetAsync(d_ws, 0, esum_end * sizeof(float), stream);
    hipMemsetAsync((void*)ws_flags, 0, (size_t)65536 * sizeof(float), stream);

    prep_kernel<<<260, 256, 0, stream>>>(z_e, embed, ws_xn, ws_wnorm, ws_whi, ws_wlo);
    mfma_argmin_kernel<<<1024, 256, 0, stream>>>(z_e, ws_xn, ws_wnorm,
                                                 ws_whi, ws_wlo, o_ind, ws_flags);
    epilogue_kernel<<<1024, 256, 0, stream>>>(z_e, embed, ws_xn, ws_wnorm, o_ind, ws_flags,
                                              o_zq, ws_diff, ws_esum, ws_onehot, nrep - 1);
    finalize_cs_kernel<<<1, 1024, 0, stream>>>(cluster_size, ws_onehot, ws_diff,
                                               o_diff, o_ncs, ws_n, nrep);
    finalize_embed_kernel<<<64, 256, 0, stream>>>(embed_avg, ws_esum, o_ncs, ws_n,
                                                  o_ne, o_nea, nrep);
}

// Round 12
// 370.070 us; speedup vs baseline: 1.1513x; 1.1513x over previous
//
#include <hip/hip_runtime.h>
#include <math.h>

#define T_TOK 65536
#define K_CODE 1024
#define E_DIM 64
#define DECAYF 0.99f
#define EPSF 1e-5f
#define MARG2 8e-5f  // > 2E, E<=~2.4e-5 = bound on |dist_mfma - dist_emul|

typedef __attribute__((ext_vector_type(8))) short short8;
typedef __attribute__((ext_vector_type(4))) float fx4;

// --- exact-rounding helpers: block ffp-contract=fast fusion ---
__device__ __forceinline__ float mul_nf(float a, float b) {
#pragma clang fp contract(off)
    return a * b;
}
__device__ __forceinline__ float add_nf(float a, float b) {
#pragma clang fp contract(off)
    return a + b;
}
__device__ __forceinline__ float sub_nf(float a, float b) {
#pragma clang fp contract(off)
    return a - b;
}

__device__ __forceinline__ unsigned short bf16_rn(float f) {
    union { float f; unsigned u; } v; v.f = f;
    unsigned r = v.u + 0x7fffu + ((v.u >> 16) & 1u);
    return (unsigned short)(r >> 16);
}
__device__ __forceinline__ float bf16_up(unsigned short h) {
    union { unsigned u; float f; } v; v.u = ((unsigned)h) << 16;
    return v.f;
}

// numpy pairwise_sum for n=64 of elementwise squares (products rounded
// separately, 8 strided accumulators, fixed combine tree).
__device__ __forceinline__ float np_sq_sum64(const float* v) {
    float r[8];
#pragma unroll
    for (int j = 0; j < 8; ++j) r[j] = mul_nf(v[j], v[j]);
#pragma unroll
    for (int i = 8; i < 64; i += 8) {
#pragma unroll
        for (int j = 0; j < 8; ++j) r[j] = add_nf(r[j], mul_nf(v[i + j], v[i + j]));
    }
    float s01 = add_nf(r[0], r[1]);
    float s23 = add_nf(r[2], r[3]);
    float s45 = add_nf(r[4], r[5]);
    float s67 = add_nf(r[6], r[7]);
    return add_nf(add_nf(s01, s23), add_nf(s45, s67));
}

// rows [0,T): np-exact ||x||^2 per token. rows [T, T+K): np-exact wnorm +
// bf16 hi/lo split of the code row.
__global__ __launch_bounds__(256) void prep_kernel(const float* __restrict__ z_e,
                                                   const float* __restrict__ embed,
                                                   float* __restrict__ xn_out,
                                                   float* __restrict__ wnorm_out,
                                                   unsigned short* __restrict__ whi,
                                                   unsigned short* __restrict__ wlo) {
    int row = blockIdx.x * 256 + threadIdx.x;
    if (row < T_TOK) {
        xn_out[row] = np_sq_sum64(z_e + (size_t)row * E_DIM);
    } else {
        int k = row - T_TOK;
        const float* w = embed + (size_t)k * E_DIM;
        wnorm_out[k] = np_sq_sum64(w);
#pragma unroll
        for (int i = 0; i < 64; ++i) {
            float e = w[i];
            unsigned short h = bf16_rn(e);
            whi[(size_t)k * 64 + i] = h;
            wlo[(size_t)k * 64 + i] = bf16_rn(e - bf16_up(h));
        }
    }
}

// Block = 256 thr = 4 waves; wave owns one 16-token M-tile, scans all 1024
// codes as 64 16-code N-tiles, unrolled x2 (8 B-frag loads hoisted per body).
// 3-pass bf16-split MFMA in 3 independent 2-deep chains (hh, lh, hl), summed
// in fp32. dist via the SAME np-exact xn/wn and same final rounding ops as
// the emulated path -> |dist_mfma - dist_emul| <= E << MARG2/2.
// Branch-free top-2; after cross-lane merge: gap > MARG2 -> provable np
// argmin; else flag for exact wave-parallel rescan in the epilogue.
__global__ __launch_bounds__(256) void mfma_argmin_kernel(const float* __restrict__ z_e,
                                                          const float* __restrict__ xn_ws,
                                                          const float* __restrict__ wnorm_ws,
                                                          const unsigned short* __restrict__ whi,
                                                          const unsigned short* __restrict__ wlo,
                                                          float* __restrict__ out_ind,
                                                          float* __restrict__ flags) {
    int lane = threadIdx.x & 63;
    int wave = threadIdx.x >> 6;
    int quad = lane >> 4;
    int lmod = lane & 15;
    int t0 = blockIdx.x * 64 + wave * 16;

    // A fragments: token = t0+lmod, dims q*32 + quad*8 + j; bf16 hi/lo in-reg
    short8 ah[2], al[2];
#pragma unroll
    for (int q = 0; q < 2; ++q) {
        const float* xp = z_e + (size_t)(t0 + lmod) * E_DIM + q * 32 + quad * 8;
#pragma unroll
        for (int j = 0; j < 8; ++j) {
            float e = xp[j];
            unsigned short h = bf16_rn(e);
            ah[q][j] = (short)h;
            al[q][j] = (short)bf16_rn(e - bf16_up(h));
        }
    }

    fx4 xnv = *(const fx4*)(xn_ws + t0 + quad * 4);

    float m1[4], m2[4];
    int i1[4];
#pragma unroll
    for (int r = 0; r < 4; ++r) { m1[r] = m2[r] = INFINITY; i1[r] = 0; }

    const unsigned short* hp = whi + (size_t)lmod * 64 + quad * 8;
    const unsigned short* lp = wlo + (size_t)lmod * 64 + quad * 8;

    for (int n = 0; n < 64; n += 2) {
        size_t o0 = (size_t)n * 1024;
        size_t o1 = o0 + 1024;
        short8 bh00 = *(const short8*)(hp + o0);
        short8 bh01 = *(const short8*)(hp + o0 + 32);
        short8 bl00 = *(const short8*)(lp + o0);
        short8 bl01 = *(const short8*)(lp + o0 + 32);
        short8 bh10 = *(const short8*)(hp + o1);
        short8 bh11 = *(const short8*)(hp + o1 + 32);
        short8 bl10 = *(const short8*)(lp + o1);
        short8 bl11 = *(const short8*)(lp + o1 + 32);
        float wn0 = wnorm_ws[n * 16 + lmod];
        float wn1 = wnorm_ws[n * 16 + 16 + lmod];

        fx4 z = {0.f, 0.f, 0.f, 0.f};
        fx4 hh = __builtin_amdgcn_mfma_f32_16x16x32_bf16(ah[0], bh00, z, 0, 0, 0);
        hh = __builtin_amdgcn_mfma_f32_16x16x32_bf16(ah[1], bh01, hh, 0, 0, 0);
        fx4 lh = __builtin_amdgcn_mfma_f32_16x16x32_bf16(al[0], bh00, z, 0, 0, 0);
        lh = __builtin_amdgcn_mfma_f32_16x16x32_bf16(al[1], bh01, lh, 0, 0, 0);
        fx4 hl = __builtin_amdgcn_mfma_f32_16x16x32_bf16(ah[0], bl00, z, 0, 0, 0);
        hl = __builtin_amdgcn_mfma_f32_16x16x32_bf16(ah[1], bl01, hl, 0, 0, 0);
        fx4 hh1 = __builtin_amdgcn_mfma_f32_16x16x32_bf16(ah[0], bh10, z, 0, 0, 0);
        hh1 = __builtin_amdgcn_mfma_f32_16x16x32_bf16(ah[1], bh11, hh1, 0, 0, 0);
        fx4 lh1 = __builtin_amdgcn_mfma_f32_16x16x32_bf16(al[0], bh10, z, 0, 0, 0);
        lh1 = __builtin_amdgcn_mfma_f32_16x16x32_bf16(al[1], bh11, lh1, 0, 0, 0);
        fx4 hl1 = __builtin_amdgcn_mfma_f32_16x16x32_bf16(ah[0], bl10, z, 0, 0, 0);
        hl1 = __builtin_amdgcn_mfma_f32_16x16x32_bf16(ah[1], bl11, hl1, 0, 0, 0);

        int code0 = n * 16 + lmod;
#pragma unroll
        for (int r = 0; r < 4; ++r) {
            float d = (hh[r] + lh[r]) + hl[r];
            float dist = add_nf(sub_nf(xnv[r], d + d), wn0);
            float t = fmaxf(m1[r], dist);
            m2[r] = fminf(m2[r], t);
            bool l = dist < m1[r];
            i1[r] = l ? code0 : i1[r];
            m1[r] = fminf(m1[r], dist);

            float d1 = (hh1[r] + lh1[r]) + hl1[r];
            float dist1 = add_nf(sub_nf(xnv[r], d1 + d1), wn1);
            float t1 = fmaxf(m1[r], dist1);
            m2[r] = fminf(m2[r], t1);
            bool l1 = dist1 < m1[r];
            i1[r] = l1 ? (code0 + 16) : i1[r];
            m1[r] = fminf(m1[r], dist1);
        }
    }

#pragma unroll
    for (int s = 1; s < 16; s <<= 1) {
#pragma unroll
        for (int r = 0; r < 4; ++r) {
            float o1v = __shfl_xor(m1[r], s, 64);
            int oi = __shfl_xor(i1[r], s, 64);
            float o2v = __shfl_xor(m2[r], s, 64);
            float mx = fmaxf(m1[r], o1v);
            m2[r] = fminf(fminf(m2[r], o2v), mx);
            if (o1v < m1[r]) { m1[r] = o1v; i1[r] = oi; }  // tie -> flagged anyway
        }
    }

    if (lmod == 0) {
#pragma unroll
        for (int r = 0; r < 4; ++r) {
            int token = t0 + quad * 4 + r;
            out_ind[token] = (float)i1[r];
            if (m2[r] - m1[r] <= MARG2) flags[token] = 1.0f;
        }
    }
}

// ONE TOKEN PER WAVE (16384 blocks x 4 waves = 65536 waves): kills the
// round-11 latency serialization (16-token serial loop at 16 waves/CU,
// VALUBusy 4.4%). Flagged tokens get the wave-parallel exact rescan
// (lane c handles codes c+64j, verified chain, np-first-index merge) —
// wave-uniform branch, no divergence. Then z_q / diff / coalesced scatter.
__global__ __launch_bounds__(256) void epilogue_kernel(const float* __restrict__ z_e,
                                                       const float* __restrict__ embed,
                                                       const float* __restrict__ xn_ws,
                                                       const float* __restrict__ wnorm_ws,
                                                       float* __restrict__ out_ind,
                                                       const float* __restrict__ flags,
                                                       float* __restrict__ out_zq,
                                                       float* __restrict__ diff_rep,
                                                       float* __restrict__ esum_rep,
                                                       float* __restrict__ onehot_rep,
                                                       int rep_mask) {
    __shared__ float xs[4][64];
    __shared__ float sdiff[4];
    int lane = threadIdx.x & 63;
    int wave = threadIdx.x >> 6;
    int t = blockIdx.x * 4 + wave;
    int rep = blockIdx.x & rep_mask;
    float* esum = esum_rep + (size_t)rep * (K_CODE * E_DIM);
    float* onehot = onehot_rep + (size_t)rep * K_CODE;

    float xv = z_e[(size_t)t * E_DIM + lane];
    int bi = (int)out_ind[t];

    if (flags[t] != 0.f) {
        xs[wave][lane] = xv;
        __builtin_amdgcn_s_waitcnt(0xC07F);  // lgkmcnt(0): stage visible wave-wide
        float xn_t = xn_ws[t];
        float bestd = INFINITY;
        int besti = 0;
        for (int c = 0; c < 16; ++c) {
            int code = lane + (c << 6);
            const float* wr = embed + (size_t)code * E_DIM;
            float d = 0.f;
#pragma unroll
            for (int i = 0; i < 64; i += 4) {
                float4 wc = *(const float4*)(wr + i);
                d = __builtin_fmaf(xs[wave][i + 0], wc.x, d);
                d = __builtin_fmaf(xs[wave][i + 1], wc.y, d);
                d = __builtin_fmaf(xs[wave][i + 2], wc.z, d);
                d = __builtin_fmaf(xs[wave][i + 3], wc.w, d);
            }
            float dist = add_nf(sub_nf(xn_t, d + d), wnorm_ws[code]);
            if (dist < bestd) { bestd = dist; besti = code; }  // ascending in-lane
        }
#pragma unroll
        for (int s = 1; s < 64; s <<= 1) {
            float od = __shfl_xor(bestd, s, 64);
            int oi = __shfl_xor(besti, s, 64);
            if (od < bestd || (od == bestd && oi < besti)) { bestd = od; besti = oi; }
        }
        bi = besti;
        if (lane == 0) out_ind[t] = (float)bi;
    }

    // np order: r = fl(z_q - z_e); out = fl(z_e + r)
    float wv = embed[(size_t)bi * E_DIM + lane];
    float rr = sub_nf(wv, xv);
    out_zq[(size_t)t * E_DIM + lane] = add_nf(xv, rr);
    float ds = rr * rr;

    atomicAdd(&esum[(size_t)bi * E_DIM + lane], xv);  // coalesced 256B row
    if (lane == 0) atomicAdd(&onehot[bi], 1.0f);

#pragma unroll
    for (int o = 32; o > 0; o >>= 1) ds += __shfl_down(ds, o, 64);
    if (lane == 0) sdiff[wave] = ds;
    __syncthreads();
    if (threadIdx.x == 0)
        atomicAdd(&diff_rep[blockIdx.x & 63],
                  ((sdiff[0] + sdiff[1]) + (sdiff[2] + sdiff[3])));
}

// ncs, n, diff: single block (tiny)
__global__ __launch_bounds__(1024) void finalize_cs_kernel(const float* __restrict__ cluster_size,
                                                           const float* __restrict__ onehot_rep,
                                                           const float* __restrict__ diff_rep,
                                                           float* __restrict__ out_diff,
                                                           float* __restrict__ out_ncs,
                                                           float* __restrict__ ws_n,
                                                           int nrep) {
    int k = threadIdx.x;
    float oh = 0.f;
    for (int r = 0; r < nrep; ++r) oh += onehot_rep[(size_t)r * K_CODE + k];
    float ncs = DECAYF * cluster_size[k] + (1.0f - DECAYF) * oh;
    out_ncs[k] = ncs;

    __shared__ float red[1024];
    red[k] = ncs;
    __syncthreads();
#pragma unroll
    for (int s = 512; s > 0; s >>= 1) {
        if (k < s) red[k] += red[k + s];
        __syncthreads();
    }
    if (k == 0) {
        ws_n[0] = red[0];
        float dsum = 0.f;
        for (int r = 0; r < 64; ++r) dsum += diff_rep[r];
        out_diff[0] = dsum * (1.0f / 4194304.0f);  // /2^22 exact
    }
}

// embed_avg / embed update spread across 64 blocks
__global__ __launch_bounds__(256) void finalize_embed_kernel(const float* __restrict__ embed_avg,
                                                             const float* __restrict__ esum_rep,
                                                             const float* __restrict__ out_ncs,
                                                             const float* __restrict__ ws_n,
                                                             float* __restrict__ out_ne,
                                                             float* __restrict__ out_nea,
                                                             int nrep) {
    int gid = blockIdx.x * 256 + threadIdx.x;
    int k = gid >> 4;
    int c = gid & 15;
    float n = ws_n[0];
    float ncs = out_ncs[k];
    float cs = (ncs + EPSF) / (n + (float)K_CODE * EPSF) * n;

    size_t off = (size_t)k * E_DIM + (size_t)c * 4;
    float4 s4 = make_float4(0.f, 0.f, 0.f, 0.f);
    for (int r = 0; r < nrep; ++r) {
        float4 v = *reinterpret_cast<const float4*>(esum_rep + (size_t)r * (K_CODE * E_DIM) + off);
        s4.x += v.x; s4.y += v.y; s4.z += v.z; s4.w += v.w;
    }
    float4 a = *reinterpret_cast<const float4*>(embed_avg + off);
    float4 nea, ne;
    nea.x = DECAYF * a.x + (1.0f - DECAYF) * s4.x;
    nea.y = DECAYF * a.y + (1.0f - DECAYF) * s4.y;
    nea.z = DECAYF * a.z + (1.0f - DECAYF) * s4.z;
    nea.w = DECAYF * a.w + (1.0f - DECAYF) * s4.w;
    ne.x = nea.x / cs; ne.y = nea.y / cs; ne.z = nea.z / cs; ne.w = nea.w / cs;
    *reinterpret_cast<float4*>(out_nea + off) = nea;
    *reinterpret_cast<float4*>(out_ne + off) = ne;
}

extern "C" void kernel_launch(void* const* d_in, const int* in_sizes, int n_in,
                              void* d_out, int out_size, void* d_ws, size_t ws_size,
                              hipStream_t stream) {
    const float* z_e = (const float*)d_in[0];
    const float* embed = (const float*)d_in[1];
    const float* cluster_size = (const float*)d_in[2];
    const float* embed_avg = (const float*)d_in[3];

    float* out = (float*)d_out;
    float* o_zq = out;                   // 4194304
    float* o_diff = out + 4194304;       // 1
    float* o_ind = out + 4194305;        // 65536
    float* o_ne = out + 4194305 + 65536; // 65536
    float* o_ncs = o_ne + 65536;         // 1024
    float* o_nea = o_ncs + 1024;         // 65536

    // ws layout (floats), adaptive in nrep:
    // [0,1024) wnorm | [1024,1088) diff reps | [1089] n | [2048,10240) onehot reps
    // [10240, E) esum reps, E = 10240 + nrep*65536
    // [E, +65536) xn | [+65536, +131072) flags
    // [+131072, +163840) w_hi (ushort) | [+163840, +196608) w_lo (ushort)
    int nrep = 8;
    while (nrep > 1 &&
           ws_size < (size_t)(10240 + (size_t)nrep * 65536 + 196608) * 4) nrep >>= 1;

    float* ws = (float*)d_ws;
    float* ws_wnorm = ws;
    float* ws_diff_rep = ws + 1024;  // 64 replicas
    float* ws_n = ws + 1089;
    float* ws_onehot = ws + 2048;
    float* ws_esum = ws + 10240;
    size_t esum_end = 10240 + (size_t)nrep * 65536;
    float* ws_xn = ws + esum_end;
    float* ws_flags = ws + esum_end + 65536;
    unsigned short* ws_whi = (unsigned short*)(ws + esum_end + 131072);
    unsigned short* ws_wlo = (unsigned short*)(ws + esum_end + 163840);

    hipMemsetAsync(d_ws, 0, esum_end * sizeof(float), stream);
    hipMemsetAsync((void*)ws_flags, 0, (size_t)65536 * sizeof(float), stream);

    prep_kernel<<<260, 256, 0, stream>>>(z_e, embed, ws_xn, ws_wnorm, ws_whi, ws_wlo);
    mfma_argmin_kernel<<<1024, 256, 0, stream>>>(z_e, ws_xn, ws_wnorm,
                                                 ws_whi, ws_wlo, o_ind, ws_flags);
    epilogue_kernel<<<16384, 256, 0, stream>>>(z_e, embed, ws_xn, ws_wnorm, o_ind, ws_flags,
                                               o_zq, ws_diff_rep, ws_esum, ws_onehot,
                                               nrep - 1);
    finalize_cs_kernel<<<1, 1024, 0, stream>>>(cluster_size, ws_onehot, ws_diff_rep,
                                               o_diff, o_ncs, ws_n, nrep);
    finalize_embed_kernel<<<64, 256, 0, stream>>>(embed_avg, ws_esum, o_ncs, ws_n,
                                                  o_ne, o_nea, nrep);
}